// Round 2
// baseline (864.131 us; speedup 1.0000x reference)
//
#include <hip/hip_runtime.h>
#include <hip/hip_bf16.h>

#define N_TOK 4096
#define DIM   1024
#define NEXP  8
#define FDIM  4096
#define KCAP  512

typedef __attribute__((ext_vector_type(8))) short bf16x8;
typedef __attribute__((ext_vector_type(4))) float floatx4;

__device__ inline unsigned short f2bf(float f) {
  union { float f; unsigned int i; } v; v.f = f;
  unsigned int r = v.i + 0x7fffu + ((v.i >> 16) & 1u);
  return (unsigned short)(r >> 16);
}

// ---------------- router: logits fp64 from fp32 inputs, softmax fp64 --------
__global__ __launch_bounds__(256)
void router_kernel(const float* __restrict__ x,
                   const float* __restrict__ Ws,
                   const float* __restrict__ bs,
                   float* __restrict__ probs_t) {
  int token = blockIdx.x * 4 + (threadIdx.x >> 6);
  int lane  = threadIdx.x & 63;
  const float* xr = x + (size_t)token * DIM;
  double acc[NEXP];
#pragma unroll
  for (int e = 0; e < NEXP; e++) acc[e] = 0.0;
#pragma unroll
  for (int c = 0; c < 4; c++) {
    int d0 = (c * 64 + lane) * 4;
    float4 xv = *(const float4*)&xr[d0];
    float xa[4] = {xv.x, xv.y, xv.z, xv.w};
#pragma unroll
    for (int q = 0; q < 4; q++) {
      const float* wr = &Ws[(size_t)(d0 + q) * NEXP];
      float4 w0 = *(const float4*)&wr[0];
      float4 w1 = *(const float4*)&wr[4];
      double xs = (double)xa[q];
      acc[0] += xs * (double)w0.x; acc[1] += xs * (double)w0.y;
      acc[2] += xs * (double)w0.z; acc[3] += xs * (double)w0.w;
      acc[4] += xs * (double)w1.x; acc[5] += xs * (double)w1.y;
      acc[6] += xs * (double)w1.z; acc[7] += xs * (double)w1.w;
    }
  }
#pragma unroll
  for (int off = 32; off > 0; off >>= 1)
#pragma unroll
    for (int e = 0; e < NEXP; e++) acc[e] += __shfl_down(acc[e], off, 64);
  if (lane == 0) {
    double mx = -1e300;
#pragma unroll
    for (int e = 0; e < NEXP; e++) { acc[e] += (double)bs[e]; if (acc[e] > mx) mx = acc[e]; }
    double s = 0.0, p[NEXP];
#pragma unroll
    for (int e = 0; e < NEXP; e++) { p[e] = exp(acc[e] - mx); s += p[e]; }
#pragma unroll
    for (int e = 0; e < NEXP; e++) probs_t[(size_t)e * N_TOK + token] = (float)(p[e] / s);
  }
}

// ---------------- top-k per expert: stable bitonic sort (desc), keep 512 ----
__global__ __launch_bounds__(1024)
void topk_kernel(const float* __restrict__ probs_t, int* __restrict__ routes,
                 float* __restrict__ vals) {
  int e = blockIdx.x;
  __shared__ float sv[N_TOK];
  __shared__ int   si[N_TOK];
  int t = threadIdx.x;
  for (int i = t; i < N_TOK; i += 1024) { sv[i] = probs_t[(size_t)e * N_TOK + i]; si[i] = i; }
  __syncthreads();
  for (int k = 2; k <= N_TOK; k <<= 1) {
    for (int j = k >> 1; j > 0; j >>= 1) {
      for (int b = t; b < N_TOK / 2; b += 1024) {
        int i = ((b & ~(j - 1)) << 1) | (b & (j - 1));
        int p = i | j;
        bool desc = ((i & k) == 0);
        float a = sv[i], bb = sv[p];
        int ia = si[i], ib = si[p];
        // rank order: higher prob first; ties -> lower index first (stable)
        bool ihi = (a > bb) || (a == bb && ia < ib);
        if (desc ? !ihi : ihi) {
          sv[i] = bb; sv[p] = a;
          si[i] = ib; si[p] = ia;
        }
      }
      __syncthreads();
    }
  }
  for (int i = t; i < KCAP; i += 1024) {
    routes[e * KCAP + i] = si[i];
    vals[e * KCAP + i]   = sv[i];
  }
}

// ---------------- x fp32 -> bf16 --------------------------------------------
__global__ __launch_bounds__(256)
void convx_kernel(const float* __restrict__ x, unsigned short* __restrict__ xb) {
  int i = (blockIdx.x * 256 + threadIdx.x) * 4;
  float4 v = *(const float4*)&x[i];
  ushort4 o;
  o.x = f2bf(v.x); o.y = f2bf(v.y); o.z = f2bf(v.z); o.w = f2bf(v.w);
  *(ushort4*)&xb[i] = o;
}

// ------- fp32 transpose + bf16 convert per expert: src[R][C] -> dst[C][R] ---
__global__ __launch_bounds__(256)
void transpose_kernel(const float* __restrict__ src,
                      unsigned short* __restrict__ dst, int R, int C) {
  size_t off = (size_t)blockIdx.z * R * C;
  __shared__ unsigned short tile[32][40];
  int t = threadIdx.x;
  int r0 = blockIdx.y * 32, c0 = blockIdx.x * 32;
  int tr = t >> 3, tc = (t & 7) * 4;
  float4 v = *(const float4*)&src[off + (size_t)(r0 + tr) * C + (c0 + tc)];
  tile[tr][tc + 0] = f2bf(v.x);
  tile[tr][tc + 1] = f2bf(v.y);
  tile[tr][tc + 2] = f2bf(v.z);
  tile[tr][tc + 3] = f2bf(v.w);
  __syncthreads();
  ushort4 o;
  o.x = tile[tc + 0][tr];
  o.y = tile[tc + 1][tr];
  o.z = tile[tc + 2][tr];
  o.w = tile[tc + 3][tr];
  *(ushort4*)&dst[off + (size_t)(c0 + tr) * R + (r0 + tc)] = o;
}

// ---------------- GEMM1: h[e][m][f] = gelu(xb[routes] @ W1t^T + b1) ---------
__global__ __launch_bounds__(256, 2)
void gemm1_kernel(const unsigned short* __restrict__ xb,
                  const unsigned short* __restrict__ w1t,   // [E][F][D] bf16
                  const float* __restrict__ b1,
                  const int* __restrict__ routes,
                  unsigned short* __restrict__ h) {
  int e = blockIdx.z, mt = blockIdx.y, nt = blockIdx.x;
  __shared__ unsigned short As[128][72];
  __shared__ unsigned short Bs[128][72];
  int t = threadIdx.x;
  int lane = t & 63, wave = t >> 6;
  int wm = (wave >> 1) * 64, wn = (wave & 1) * 64;
  int srow = t >> 1, shalf = (t & 1) * 32;
  int tokenRow = routes[e * KCAP + mt * 128 + srow];
  const unsigned short* aSrc = xb + (size_t)tokenRow * DIM + shalf;
  const unsigned short* bSrc = w1t + ((size_t)e * FDIM + (size_t)(nt * 128 + srow)) * DIM + shalf;
  int fr = lane & 15, fq = lane >> 4;
  floatx4 acc[4][4];
#pragma unroll
  for (int i = 0; i < 4; i++)
#pragma unroll
    for (int j = 0; j < 4; j++) acc[i][j] = (floatx4)0.0f;

  for (int k0 = 0; k0 < DIM; k0 += 64) {
    uint4 av[4], bv[4];
#pragma unroll
    for (int i = 0; i < 4; i++) av[i] = *(const uint4*)(aSrc + k0 + i * 8);
#pragma unroll
    for (int i = 0; i < 4; i++) bv[i] = *(const uint4*)(bSrc + k0 + i * 8);
    __syncthreads();
#pragma unroll
    for (int i = 0; i < 4; i++) *(uint4*)&As[srow][shalf + i * 8] = av[i];
#pragma unroll
    for (int i = 0; i < 4; i++) *(uint4*)&Bs[srow][shalf + i * 8] = bv[i];
    __syncthreads();
#pragma unroll
    for (int ks = 0; ks < 2; ks++) {
      bf16x8 af[4], bfr[4];
#pragma unroll
      for (int i = 0; i < 4; i++)
        af[i] = *(const bf16x8*)&As[wm + i * 16 + fr][ks * 32 + fq * 8];
#pragma unroll
      for (int j = 0; j < 4; j++)
        bfr[j] = *(const bf16x8*)&Bs[wn + j * 16 + fr][ks * 32 + fq * 8];
#pragma unroll
      for (int i = 0; i < 4; i++)
#pragma unroll
        for (int j = 0; j < 4; j++)
          acc[i][j] = __builtin_amdgcn_mfma_f32_16x16x32_bf16(af[i], bfr[j], acc[i][j], 0, 0, 0);
    }
  }
#pragma unroll
  for (int i = 0; i < 4; i++) {
#pragma unroll
    for (int r = 0; r < 4; r++) {
      int m = mt * 128 + wm + i * 16 + fq * 4 + r;
      size_t hrow = ((size_t)e * KCAP + m) * FDIM;
#pragma unroll
      for (int j = 0; j < 4; j++) {
        int f = nt * 128 + wn + j * 16 + fr;
        float v = acc[i][j][r] + b1[e * FDIM + f];
        float u = 0.7978845608028654f * (v + 0.044715f * v * v * v);
        float g = 0.5f * v * (1.0f + tanhf(u));
        h[hrow + f] = f2bf(g);
      }
    }
  }
}

// ------- GEMM2 (split-K=2): out += val * (h @ W2t^T + b2), atomic fp32 ------
__global__ __launch_bounds__(256, 2)
void gemm2_kernel(const unsigned short* __restrict__ h,
                  const unsigned short* __restrict__ w2t,   // [E][D][F] bf16
                  const float* __restrict__ b2,
                  const int* __restrict__ routes,
                  const float* __restrict__ vals,
                  float* __restrict__ out) {
  int e = blockIdx.z >> 1, s = blockIdx.z & 1;
  int mt = blockIdx.y, nt = blockIdx.x;
  __shared__ unsigned short As[128][72];
  __shared__ unsigned short Bs[128][72];
  int t = threadIdx.x;
  int lane = t & 63, wave = t >> 6;
  int wm = (wave >> 1) * 64, wn = (wave & 1) * 64;
  int srow = t >> 1, shalf = (t & 1) * 32;
  const unsigned short* aSrc = h + ((size_t)e * KCAP + mt * 128 + srow) * FDIM + s * 2048 + shalf;
  const unsigned short* bSrc = w2t + ((size_t)e * DIM + (size_t)(nt * 128 + srow)) * FDIM + s * 2048 + shalf;
  int fr = lane & 15, fq = lane >> 4;
  floatx4 acc[4][4];
#pragma unroll
  for (int i = 0; i < 4; i++)
#pragma unroll
    for (int j = 0; j < 4; j++) acc[i][j] = (floatx4)0.0f;

  for (int k0 = 0; k0 < 2048; k0 += 64) {
    uint4 av[4], bv[4];
#pragma unroll
    for (int i = 0; i < 4; i++) av[i] = *(const uint4*)(aSrc + k0 + i * 8);
#pragma unroll
    for (int i = 0; i < 4; i++) bv[i] = *(const uint4*)(bSrc + k0 + i * 8);
    __syncthreads();
#pragma unroll
    for (int i = 0; i < 4; i++) *(uint4*)&As[srow][shalf + i * 8] = av[i];
#pragma unroll
    for (int i = 0; i < 4; i++) *(uint4*)&Bs[srow][shalf + i * 8] = bv[i];
    __syncthreads();
#pragma unroll
    for (int ks = 0; ks < 2; ks++) {
      bf16x8 af[4], bfr[4];
#pragma unroll
      for (int i = 0; i < 4; i++)
        af[i] = *(const bf16x8*)&As[wm + i * 16 + fr][ks * 32 + fq * 8];
#pragma unroll
      for (int j = 0; j < 4; j++)
        bfr[j] = *(const bf16x8*)&Bs[wn + j * 16 + fr][ks * 32 + fq * 8];
#pragma unroll
      for (int i = 0; i < 4; i++)
#pragma unroll
        for (int j = 0; j < 4; j++)
          acc[i][j] = __builtin_amdgcn_mfma_f32_16x16x32_bf16(af[i], bfr[j], acc[i][j], 0, 0, 0);
    }
  }
#pragma unroll
  for (int i = 0; i < 4; i++) {
#pragma unroll
    for (int r = 0; r < 4; r++) {
      int m = mt * 128 + wm + i * 16 + fq * 4 + r;
      int slot = e * KCAP + m;
      int token = routes[slot];
      float val = vals[slot];
#pragma unroll
      for (int j = 0; j < 4; j++) {
        int d = nt * 128 + wn + j * 16 + fr;
        float v = acc[i][j][r];
        if (s == 0) v += b2[e * DIM + d];
        atomicAdd(&out[(size_t)token * DIM + d], v * val);
      }
    }
  }
}

extern "C" void kernel_launch(void* const* d_in, const int* in_sizes, int n_in,
                              void* d_out, int out_size, void* d_ws, size_t ws_size,
                              hipStream_t stream) {
  const float* x  = (const float*)d_in[0];
  const float* Ws = (const float*)d_in[1];
  const float* bs = (const float*)d_in[2];
  const float* W1 = (const float*)d_in[3];
  const float* b1 = (const float*)d_in[4];
  const float* W2 = (const float*)d_in[5];
  const float* b2 = (const float*)d_in[6];
  float* out = (float*)d_out;

  char* ws = (char*)d_ws;
  unsigned short* wt = (unsigned short*)ws; ws += (size_t)NEXP * FDIM * DIM * 2;  // 67 MB (shared W1t/W2t)
  unsigned short* h  = (unsigned short*)ws; ws += (size_t)NEXP * KCAP * FDIM * 2; // 33.5 MB
  unsigned short* xb = (unsigned short*)ws; ws += (size_t)N_TOK * DIM * 2;        // 8.4 MB
  float* probs  = (float*)ws; ws += (size_t)NEXP * N_TOK * 4;
  int*   routes = (int*)ws;   ws += NEXP * KCAP * 4;
  float* vals   = (float*)ws; ws += NEXP * KCAP * 4;

  hipMemsetAsync(out, 0, (size_t)N_TOK * DIM * sizeof(float), stream);
  router_kernel<<<N_TOK / 4, 256, 0, stream>>>(x, Ws, bs, probs);
  topk_kernel<<<NEXP, 1024, 0, stream>>>(probs, routes, vals);
  convx_kernel<<<N_TOK * DIM / 1024, 256, 0, stream>>>(x, xb);
  // W1 [E][D][F] fp32 -> wt [E][F][D] bf16
  transpose_kernel<<<dim3(FDIM / 32, DIM / 32, NEXP), 256, 0, stream>>>(W1, wt, DIM, FDIM);
  gemm1_kernel<<<dim3(FDIM / 128, KCAP / 128, NEXP), 256, 0, stream>>>(xb, wt, b1, routes, h);
  // W2 [E][F][D] fp32 -> wt [E][D][F] bf16
  transpose_kernel<<<dim3(DIM / 32, FDIM / 32, NEXP), 256, 0, stream>>>(W2, wt, FDIM, DIM);
  gemm2_kernel<<<dim3(DIM / 128, KCAP / 128, NEXP * 2), 256, 0, stream>>>(h, wt, b2, routes, vals, out);
}

// Round 3
// 792.183 us; speedup vs baseline: 1.0908x; 1.0908x over previous
//
#include <hip/hip_runtime.h>
#include <hip/hip_bf16.h>

#define N_TOK 4096
#define DIM   1024
#define NEXP  8
#define FDIM  4096
#define KCAP  512

typedef __attribute__((ext_vector_type(8))) short bf16x8;
typedef __attribute__((ext_vector_type(4))) float floatx4;

__device__ inline unsigned short f2bf(float f) {
  union { float f; unsigned int i; } v; v.f = f;
  unsigned int r = v.i + 0x7fffu + ((v.i >> 16) & 1u);
  return (unsigned short)(r >> 16);
}

// ---------------- router: logits fp64 from fp32 inputs, softmax fp64 --------
__global__ __launch_bounds__(256)
void router_kernel(const float* __restrict__ x,
                   const float* __restrict__ Ws,
                   const float* __restrict__ bs,
                   float* __restrict__ probs_t) {
  int token = blockIdx.x * 4 + (threadIdx.x >> 6);
  int lane  = threadIdx.x & 63;
  const float* xr = x + (size_t)token * DIM;
  double acc[NEXP];
#pragma unroll
  for (int e = 0; e < NEXP; e++) acc[e] = 0.0;
#pragma unroll
  for (int c = 0; c < 4; c++) {
    int d0 = (c * 64 + lane) * 4;
    float4 xv = *(const float4*)&xr[d0];
    float xa[4] = {xv.x, xv.y, xv.z, xv.w};
#pragma unroll
    for (int q = 0; q < 4; q++) {
      const float* wr = &Ws[(size_t)(d0 + q) * NEXP];
      float4 w0 = *(const float4*)&wr[0];
      float4 w1 = *(const float4*)&wr[4];
      double xs = (double)xa[q];
      acc[0] += xs * (double)w0.x; acc[1] += xs * (double)w0.y;
      acc[2] += xs * (double)w0.z; acc[3] += xs * (double)w0.w;
      acc[4] += xs * (double)w1.x; acc[5] += xs * (double)w1.y;
      acc[6] += xs * (double)w1.z; acc[7] += xs * (double)w1.w;
    }
  }
#pragma unroll
  for (int off = 32; off > 0; off >>= 1)
#pragma unroll
    for (int e = 0; e < NEXP; e++) acc[e] += __shfl_down(acc[e], off, 64);
  if (lane == 0) {
    double mx = -1e300;
#pragma unroll
    for (int e = 0; e < NEXP; e++) { acc[e] += (double)bs[e]; if (acc[e] > mx) mx = acc[e]; }
    double s = 0.0, p[NEXP];
#pragma unroll
    for (int e = 0; e < NEXP; e++) { p[e] = exp(acc[e] - mx); s += p[e]; }
#pragma unroll
    for (int e = 0; e < NEXP; e++) probs_t[(size_t)e * N_TOK + token] = (float)(p[e] / s);
  }
}

// ------- top-k per expert: radix-histogram select of 512 from 4096 ---------
// Positive fp32 are uint-monotonic. 3 levels: bits[31:20], [19:8], [7:0].
// Select v > T, plus first R ties (index order) -> matches stable np top-k set.
__global__ __launch_bounds__(1024)
void topk_kernel(const float* __restrict__ probs_t, int* __restrict__ routes,
                 float* __restrict__ vals) {
  int e = blockIdx.x;
  const float* P = probs_t + (size_t)e * N_TOK;
  __shared__ int hist[4096];
  __shared__ int hist2[4096];
  __shared__ int scan[1024];
  __shared__ int sB, sR, sCnt;
  __shared__ unsigned int sPrefix, sMask;
  int t = threadIdx.x;

  float vv[4];
  unsigned int vb[4];
  float4 v4 = *(const float4*)&P[t * 4];
  vv[0] = v4.x; vv[1] = v4.y; vv[2] = v4.z; vv[3] = v4.w;
#pragma unroll
  for (int q = 0; q < 4; q++) vb[q] = __float_as_uint(vv[q]);

  if (t == 0) { sR = KCAP; sPrefix = 0u; sMask = 0u; sCnt = 0; }
  __syncthreads();

  for (int level = 0; level < 3; level++) {
    int nb    = (level < 2) ? 4096 : 256;
    int shift = (level == 0) ? 20 : (level == 1) ? 8 : 0;
    for (int i = t; i < nb; i += 1024) hist[i] = 0;
    __syncthreads();
    unsigned int msk = sMask, pfx = sPrefix;
#pragma unroll
    for (int q = 0; q < 4; q++)
      if ((vb[q] & msk) == pfx)
        atomicAdd(&hist[(vb[q] >> shift) & (nb - 1)], 1);
    __syncthreads();
    // inclusive suffix sum over nb bins (ping-pong)
    int* src = hist; int* dst = hist2;
    for (int d = 1; d < nb; d <<= 1) {
      for (int i = t; i < nb; i += 1024)
        dst[i] = src[i] + ((i + d < nb) ? src[i + d] : 0);
      int* tmp = src; src = dst; dst = tmp;
      __syncthreads();
    }
    int R = sR;
    for (int i = t; i < nb; i += 1024) {
      int si = src[i];
      int sn = (i + 1 < nb) ? src[i + 1] : 0;
      if (si >= R && sn < R) sB = i;
    }
    __syncthreads();
    if (t == 0) {
      int B = sB;
      int strict = (B + 1 < nb) ? src[B + 1] : 0;
      sR = sR - strict;
      sPrefix |= ((unsigned int)B) << shift;
      sMask   |= ((unsigned int)(nb - 1)) << shift;
    }
    __syncthreads();
  }

  unsigned int T = sPrefix;
  int R = sR;
  // exclusive prefix of per-thread tie counts (index order)
  int cnt = 0;
#pragma unroll
  for (int q = 0; q < 4; q++) if (vb[q] == T) cnt++;
  scan[t] = cnt;
  __syncthreads();
  for (int d = 1; d < 1024; d <<= 1) {
    int v = (t >= d) ? scan[t - d] : 0;
    __syncthreads();
    scan[t] += v;
    __syncthreads();
  }
  int grank = scan[t] - cnt;
#pragma unroll
  for (int q = 0; q < 4; q++) {
    bool sel = false;
    if (vb[q] > T) sel = true;
    else if (vb[q] == T) { if (grank < R) sel = true; grank++; }
    if (sel) {
      int pos = atomicAdd(&sCnt, 1);
      routes[e * KCAP + pos] = t * 4 + q;
      vals[e * KCAP + pos]   = vv[q];
    }
  }
}

// ---------------- inverse index: token -> list of slots ---------------------
__global__ __launch_bounds__(256)
void invidx_kernel(const int* __restrict__ routes, int* __restrict__ counts,
                   int* __restrict__ inv) {
  int s = blockIdx.x * 256 + threadIdx.x;   // slot 0..4095
  int token = routes[s];
  int pos = atomicAdd(&counts[token], 1);
  inv[token * NEXP + pos] = s;
}

// ---------------- x fp32 -> bf16 --------------------------------------------
__global__ __launch_bounds__(256)
void convx_kernel(const float* __restrict__ x, unsigned short* __restrict__ xb) {
  int i = (blockIdx.x * 256 + threadIdx.x) * 4;
  float4 v = *(const float4*)&x[i];
  ushort4 o;
  o.x = f2bf(v.x); o.y = f2bf(v.y); o.z = f2bf(v.z); o.w = f2bf(v.w);
  *(ushort4*)&xb[i] = o;
}

// ------- fp32 transpose + bf16 convert per expert: src[R][C] -> dst[C][R] ---
__global__ __launch_bounds__(256)
void transpose_kernel(const float* __restrict__ src,
                      unsigned short* __restrict__ dst, int R, int C) {
  size_t off = (size_t)blockIdx.z * R * C;
  __shared__ unsigned short tile[32][40];
  int t = threadIdx.x;
  int r0 = blockIdx.y * 32, c0 = blockIdx.x * 32;
  int tr = t >> 3, tc = (t & 7) * 4;
  float4 v = *(const float4*)&src[off + (size_t)(r0 + tr) * C + (c0 + tc)];
  tile[tr][tc + 0] = f2bf(v.x);
  tile[tr][tc + 1] = f2bf(v.y);
  tile[tr][tc + 2] = f2bf(v.z);
  tile[tr][tc + 3] = f2bf(v.w);
  __syncthreads();
  ushort4 o;
  o.x = tile[tc + 0][tr];
  o.y = tile[tc + 1][tr];
  o.z = tile[tc + 2][tr];
  o.w = tile[tc + 3][tr];
  *(ushort4*)&dst[off + (size_t)(c0 + tr) * R + (r0 + tc)] = o;
}

// ---------------- GEMM1: h[e][m][f] = gelu(xb[routes] @ W1t^T + b1) ---------
__global__ __launch_bounds__(256, 2)
void gemm1_kernel(const unsigned short* __restrict__ xb,
                  const unsigned short* __restrict__ w1t,   // [E][F][D] bf16
                  const float* __restrict__ b1,
                  const int* __restrict__ routes,
                  unsigned short* __restrict__ h) {
  int e = blockIdx.z, mt = blockIdx.y, nt = blockIdx.x;
  __shared__ unsigned short As[128][72];
  __shared__ unsigned short Bs[128][72];
  int t = threadIdx.x;
  int lane = t & 63, wave = t >> 6;
  int wm = (wave >> 1) * 64, wn = (wave & 1) * 64;
  int srow = t >> 1, shalf = (t & 1) * 32;
  int tokenRow = routes[e * KCAP + mt * 128 + srow];
  const unsigned short* aSrc = xb + (size_t)tokenRow * DIM + shalf;
  const unsigned short* bSrc = w1t + ((size_t)e * FDIM + (size_t)(nt * 128 + srow)) * DIM + shalf;
  int fr = lane & 15, fq = lane >> 4;
  floatx4 acc[4][4];
#pragma unroll
  for (int i = 0; i < 4; i++)
#pragma unroll
    for (int j = 0; j < 4; j++) acc[i][j] = (floatx4)0.0f;

  for (int k0 = 0; k0 < DIM; k0 += 64) {
    uint4 av[4], bv[4];
#pragma unroll
    for (int i = 0; i < 4; i++) av[i] = *(const uint4*)(aSrc + k0 + i * 8);
#pragma unroll
    for (int i = 0; i < 4; i++) bv[i] = *(const uint4*)(bSrc + k0 + i * 8);
    __syncthreads();
#pragma unroll
    for (int i = 0; i < 4; i++) *(uint4*)&As[srow][shalf + i * 8] = av[i];
#pragma unroll
    for (int i = 0; i < 4; i++) *(uint4*)&Bs[srow][shalf + i * 8] = bv[i];
    __syncthreads();
#pragma unroll
    for (int ks = 0; ks < 2; ks++) {
      bf16x8 af[4], bfr[4];
#pragma unroll
      for (int i = 0; i < 4; i++)
        af[i] = *(const bf16x8*)&As[wm + i * 16 + fr][ks * 32 + fq * 8];
#pragma unroll
      for (int j = 0; j < 4; j++)
        bfr[j] = *(const bf16x8*)&Bs[wn + j * 16 + fr][ks * 32 + fq * 8];
#pragma unroll
      for (int i = 0; i < 4; i++)
#pragma unroll
        for (int j = 0; j < 4; j++)
          acc[i][j] = __builtin_amdgcn_mfma_f32_16x16x32_bf16(af[i], bfr[j], acc[i][j], 0, 0, 0);
    }
  }
#pragma unroll
  for (int i = 0; i < 4; i++) {
#pragma unroll
    for (int r = 0; r < 4; r++) {
      int m = mt * 128 + wm + i * 16 + fq * 4 + r;
      size_t hrow = ((size_t)e * KCAP + m) * FDIM;
#pragma unroll
      for (int j = 0; j < 4; j++) {
        int f = nt * 128 + wn + j * 16 + fr;
        float v = acc[i][j][r] + b1[e * FDIM + f];
        float u = 0.7978845608028654f * (v + 0.044715f * v * v * v);
        float g = 0.5f * v * (1.0f + tanhf(u));
        h[hrow + f] = f2bf(g);
      }
    }
  }
}

// ------- GEMM2: out_e[slot][d] = val * (h @ W2t^T + b2), plain stores -------
__global__ __launch_bounds__(256, 2)
void gemm2_kernel(const unsigned short* __restrict__ h,
                  const unsigned short* __restrict__ w2t,   // [E][D][F] bf16
                  const float* __restrict__ b2,
                  const float* __restrict__ vals,
                  float* __restrict__ out_e) {
  int e = blockIdx.z;
  int mt = blockIdx.y, nt = blockIdx.x;
  __shared__ unsigned short As[128][72];
  __shared__ unsigned short Bs[128][72];
  int t = threadIdx.x;
  int lane = t & 63, wave = t >> 6;
  int wm = (wave >> 1) * 64, wn = (wave & 1) * 64;
  int srow = t >> 1, shalf = (t & 1) * 32;
  const unsigned short* aSrc = h + ((size_t)e * KCAP + mt * 128 + srow) * FDIM + shalf;
  const unsigned short* bSrc = w2t + ((size_t)e * DIM + (size_t)(nt * 128 + srow)) * FDIM + shalf;
  int fr = lane & 15, fq = lane >> 4;
  floatx4 acc[4][4];
#pragma unroll
  for (int i = 0; i < 4; i++)
#pragma unroll
    for (int j = 0; j < 4; j++) acc[i][j] = (floatx4)0.0f;

  for (int k0 = 0; k0 < FDIM; k0 += 64) {
    uint4 av[4], bv[4];
#pragma unroll
    for (int i = 0; i < 4; i++) av[i] = *(const uint4*)(aSrc + k0 + i * 8);
#pragma unroll
    for (int i = 0; i < 4; i++) bv[i] = *(const uint4*)(bSrc + k0 + i * 8);
    __syncthreads();
#pragma unroll
    for (int i = 0; i < 4; i++) *(uint4*)&As[srow][shalf + i * 8] = av[i];
#pragma unroll
    for (int i = 0; i < 4; i++) *(uint4*)&Bs[srow][shalf + i * 8] = bv[i];
    __syncthreads();
#pragma unroll
    for (int ks = 0; ks < 2; ks++) {
      bf16x8 af[4], bfr[4];
#pragma unroll
      for (int i = 0; i < 4; i++)
        af[i] = *(const bf16x8*)&As[wm + i * 16 + fr][ks * 32 + fq * 8];
#pragma unroll
      for (int j = 0; j < 4; j++)
        bfr[j] = *(const bf16x8*)&Bs[wn + j * 16 + fr][ks * 32 + fq * 8];
#pragma unroll
      for (int i = 0; i < 4; i++)
#pragma unroll
        for (int j = 0; j < 4; j++)
          acc[i][j] = __builtin_amdgcn_mfma_f32_16x16x32_bf16(af[i], bfr[j], acc[i][j], 0, 0, 0);
    }
  }
#pragma unroll
  for (int i = 0; i < 4; i++) {
#pragma unroll
    for (int r = 0; r < 4; r++) {
      int m = mt * 128 + wm + i * 16 + fq * 4 + r;
      int slot = e * KCAP + m;
      float val = vals[slot];
#pragma unroll
      for (int j = 0; j < 4; j++) {
        int d = nt * 128 + wn + j * 16 + fr;
        float v = (acc[i][j][r] + b2[e * DIM + d]) * val;
        out_e[(size_t)slot * DIM + d] = v;
      }
    }
  }
}

// ---------------- combine: out[token] = sum over its slots of out_e ---------
__global__ __launch_bounds__(256)
void combine_kernel(const float* __restrict__ out_e, const int* __restrict__ counts,
                    const int* __restrict__ inv, float* __restrict__ out) {
  int token = blockIdx.x;
  int t = threadIdx.x;
  int c = counts[token];
  float4 acc = {0.f, 0.f, 0.f, 0.f};
  for (int i = 0; i < c; i++) {
    int slot = inv[token * NEXP + i];
    float4 v = *(const float4*)&out_e[(size_t)slot * DIM + t * 4];
    acc.x += v.x; acc.y += v.y; acc.z += v.z; acc.w += v.w;
  }
  *(float4*)&out[(size_t)token * DIM + t * 4] = acc;
}

extern "C" void kernel_launch(void* const* d_in, const int* in_sizes, int n_in,
                              void* d_out, int out_size, void* d_ws, size_t ws_size,
                              hipStream_t stream) {
  const float* x  = (const float*)d_in[0];
  const float* Ws = (const float*)d_in[1];
  const float* bs = (const float*)d_in[2];
  const float* W1 = (const float*)d_in[3];
  const float* b1 = (const float*)d_in[4];
  const float* W2 = (const float*)d_in[5];
  const float* b2 = (const float*)d_in[6];
  float* out = (float*)d_out;

  char* ws = (char*)d_ws;
  unsigned short* wt = (unsigned short*)ws; ws += (size_t)NEXP * FDIM * DIM * 2;  // 67 MB (shared W1t/W2t)
  unsigned short* h  = (unsigned short*)ws; ws += (size_t)NEXP * KCAP * FDIM * 2; // 33.5 MB
  unsigned short* xb = (unsigned short*)ws; ws += (size_t)N_TOK * DIM * 2;        // 8.4 MB
  float* out_e  = (float*)ws; ws += (size_t)NEXP * KCAP * DIM * 4;                // 16.8 MB
  float* probs  = (float*)ws; ws += (size_t)NEXP * N_TOK * 4;
  int*   routes = (int*)ws;   ws += NEXP * KCAP * 4;
  float* vals   = (float*)ws; ws += NEXP * KCAP * 4;
  int*   counts = (int*)ws;   ws += N_TOK * 4;
  int*   inv    = (int*)ws;   ws += N_TOK * NEXP * 4;

  hipMemsetAsync(counts, 0, N_TOK * sizeof(int), stream);
  router_kernel<<<N_TOK / 4, 256, 0, stream>>>(x, Ws, bs, probs);
  topk_kernel<<<NEXP, 1024, 0, stream>>>(probs, routes, vals);
  invidx_kernel<<<NEXP * KCAP / 256, 256, 0, stream>>>(routes, counts, inv);
  convx_kernel<<<N_TOK * DIM / 1024, 256, 0, stream>>>(x, xb);
  // W1 [E][D][F] fp32 -> wt [E][F][D] bf16
  transpose_kernel<<<dim3(FDIM / 32, DIM / 32, NEXP), 256, 0, stream>>>(W1, wt, DIM, FDIM);
  gemm1_kernel<<<dim3(FDIM / 128, KCAP / 128, NEXP), 256, 0, stream>>>(xb, wt, b1, routes, h);
  // W2 [E][F][D] fp32 -> wt [E][D][F] bf16
  transpose_kernel<<<dim3(DIM / 32, FDIM / 32, NEXP), 256, 0, stream>>>(W2, wt, FDIM, DIM);
  gemm2_kernel<<<dim3(DIM / 128, KCAP / 128, NEXP), 256, 0, stream>>>(h, wt, b2, vals, out_e);
  combine_kernel<<<N_TOK, 256, 0, stream>>>(out_e, counts, inv, out);
}

// Round 4
// 452.573 us; speedup vs baseline: 1.9094x; 1.7504x over previous
//
#include <hip/hip_runtime.h>
#include <hip/hip_bf16.h>

#define N_TOK 4096
#define DIM   1024
#define NEXP  8
#define FDIM  4096
#define KCAP  512

typedef __attribute__((ext_vector_type(8))) short bf16x8;
typedef __attribute__((ext_vector_type(4))) float floatx4;

__device__ inline unsigned short f2bf(float f) {
  union { float f; unsigned int i; } v; v.f = f;
  unsigned int r = v.i + 0x7fffu + ((v.i >> 16) & 1u);
  return (unsigned short)(r >> 16);
}

// async global->LDS, 16 B per lane; LDS dest = wave-uniform base + lane*16
__device__ inline void ld2lds16(const void* g, void* l) {
  __builtin_amdgcn_global_load_lds(
      (const __attribute__((address_space(1))) unsigned int*)g,
      (__attribute__((address_space(3))) unsigned int*)l,
      16, 0, 0);
}

// ---------------- router: logits fp64 from fp32 inputs, softmax fp64 --------
__global__ __launch_bounds__(256)
void router_kernel(const float* __restrict__ x,
                   const float* __restrict__ Ws,
                   const float* __restrict__ bs,
                   float* __restrict__ probs_t) {
  int token = blockIdx.x * 4 + (threadIdx.x >> 6);
  int lane  = threadIdx.x & 63;
  const float* xr = x + (size_t)token * DIM;
  double acc[NEXP];
#pragma unroll
  for (int e = 0; e < NEXP; e++) acc[e] = 0.0;
#pragma unroll
  for (int c = 0; c < 4; c++) {
    int d0 = (c * 64 + lane) * 4;
    float4 xv = *(const float4*)&xr[d0];
    float xa[4] = {xv.x, xv.y, xv.z, xv.w};
#pragma unroll
    for (int q = 0; q < 4; q++) {
      const float* wr = &Ws[(size_t)(d0 + q) * NEXP];
      float4 w0 = *(const float4*)&wr[0];
      float4 w1 = *(const float4*)&wr[4];
      double xs = (double)xa[q];
      acc[0] += xs * (double)w0.x; acc[1] += xs * (double)w0.y;
      acc[2] += xs * (double)w0.z; acc[3] += xs * (double)w0.w;
      acc[4] += xs * (double)w1.x; acc[5] += xs * (double)w1.y;
      acc[6] += xs * (double)w1.z; acc[7] += xs * (double)w1.w;
    }
  }
#pragma unroll
  for (int off = 32; off > 0; off >>= 1)
#pragma unroll
    for (int e = 0; e < NEXP; e++) acc[e] += __shfl_down(acc[e], off, 64);
  if (lane == 0) {
    double mx = -1e300;
#pragma unroll
    for (int e = 0; e < NEXP; e++) { acc[e] += (double)bs[e]; if (acc[e] > mx) mx = acc[e]; }
    double s = 0.0, p[NEXP];
#pragma unroll
    for (int e = 0; e < NEXP; e++) { p[e] = exp(acc[e] - mx); s += p[e]; }
#pragma unroll
    for (int e = 0; e < NEXP; e++) probs_t[(size_t)e * N_TOK + token] = (float)(p[e] / s);
  }
}

// ------- top-k per expert: radix-histogram select of 512 from 4096 ---------
__global__ __launch_bounds__(1024)
void topk_kernel(const float* __restrict__ probs_t, int* __restrict__ routes,
                 float* __restrict__ vals) {
  int e = blockIdx.x;
  const float* P = probs_t + (size_t)e * N_TOK;
  __shared__ int hist[4096];
  __shared__ int hist2[4096];
  __shared__ int scan[1024];
  __shared__ int sB, sR, sCnt;
  __shared__ unsigned int sPrefix, sMask;
  int t = threadIdx.x;

  float vv[4];
  unsigned int vb[4];
  float4 v4 = *(const float4*)&P[t * 4];
  vv[0] = v4.x; vv[1] = v4.y; vv[2] = v4.z; vv[3] = v4.w;
#pragma unroll
  for (int q = 0; q < 4; q++) vb[q] = __float_as_uint(vv[q]);

  if (t == 0) { sR = KCAP; sPrefix = 0u; sMask = 0u; sCnt = 0; }
  __syncthreads();

  for (int level = 0; level < 3; level++) {
    int nb    = (level < 2) ? 4096 : 256;
    int shift = (level == 0) ? 20 : (level == 1) ? 8 : 0;
    for (int i = t; i < nb; i += 1024) hist[i] = 0;
    __syncthreads();
    unsigned int msk = sMask, pfx = sPrefix;
#pragma unroll
    for (int q = 0; q < 4; q++)
      if ((vb[q] & msk) == pfx)
        atomicAdd(&hist[(vb[q] >> shift) & (nb - 1)], 1);
    __syncthreads();
    int* src = hist; int* dst = hist2;
    for (int d = 1; d < nb; d <<= 1) {
      for (int i = t; i < nb; i += 1024)
        dst[i] = src[i] + ((i + d < nb) ? src[i + d] : 0);
      int* tmp = src; src = dst; dst = tmp;
      __syncthreads();
    }
    int R = sR;
    for (int i = t; i < nb; i += 1024) {
      int si = src[i];
      int sn = (i + 1 < nb) ? src[i + 1] : 0;
      if (si >= R && sn < R) sB = i;
    }
    __syncthreads();
    if (t == 0) {
      int B = sB;
      int strict = (B + 1 < nb) ? src[B + 1] : 0;
      sR = sR - strict;
      sPrefix |= ((unsigned int)B) << shift;
      sMask   |= ((unsigned int)(nb - 1)) << shift;
    }
    __syncthreads();
  }

  unsigned int T = sPrefix;
  int R = sR;
  int cnt = 0;
#pragma unroll
  for (int q = 0; q < 4; q++) if (vb[q] == T) cnt++;
  scan[t] = cnt;
  __syncthreads();
  for (int d = 1; d < 1024; d <<= 1) {
    int v = (t >= d) ? scan[t - d] : 0;
    __syncthreads();
    scan[t] += v;
    __syncthreads();
  }
  int grank = scan[t] - cnt;
#pragma unroll
  for (int q = 0; q < 4; q++) {
    bool sel = false;
    if (vb[q] > T) sel = true;
    else if (vb[q] == T) { if (grank < R) sel = true; grank++; }
    if (sel) {
      int pos = atomicAdd(&sCnt, 1);
      routes[e * KCAP + pos] = t * 4 + q;
      vals[e * KCAP + pos]   = vv[q];
    }
  }
}

// ---------------- inverse index: token -> list of slots ---------------------
__global__ __launch_bounds__(256)
void invidx_kernel(const int* __restrict__ routes, int* __restrict__ counts,
                   int* __restrict__ inv) {
  int s = blockIdx.x * 256 + threadIdx.x;
  int token = routes[s];
  int pos = atomicAdd(&counts[token], 1);
  inv[token * NEXP + pos] = s;
}

// ---------------- x fp32 -> bf16 --------------------------------------------
__global__ __launch_bounds__(256)
void convx_kernel(const float* __restrict__ x, unsigned short* __restrict__ xb) {
  int i = (blockIdx.x * 256 + threadIdx.x) * 4;
  float4 v = *(const float4*)&x[i];
  ushort4 o;
  o.x = f2bf(v.x); o.y = f2bf(v.y); o.z = f2bf(v.z); o.w = f2bf(v.w);
  *(ushort4*)&xb[i] = o;
}

// ------- fp32 transpose + bf16 convert per expert: src[R][C] -> dst[C][R] ---
__global__ __launch_bounds__(256)
void transpose_kernel(const float* __restrict__ src,
                      unsigned short* __restrict__ dst, int R, int C) {
  size_t off = (size_t)blockIdx.z * R * C;
  __shared__ unsigned short tile[32][40];
  int t = threadIdx.x;
  int r0 = blockIdx.y * 32, c0 = blockIdx.x * 32;
  int tr = t >> 3, tc = (t & 7) * 4;
  float4 v = *(const float4*)&src[off + (size_t)(r0 + tr) * C + (c0 + tc)];
  tile[tr][tc + 0] = f2bf(v.x);
  tile[tr][tc + 1] = f2bf(v.y);
  tile[tr][tc + 2] = f2bf(v.z);
  tile[tr][tc + 3] = f2bf(v.w);
  __syncthreads();
  ushort4 o;
  o.x = tile[tc + 0][tr];
  o.y = tile[tc + 1][tr];
  o.z = tile[tc + 2][tr];
  o.w = tile[tc + 3][tr];
  *(ushort4*)&dst[off + (size_t)(c0 + tr) * R + (r0 + tc)] = o;
}

// ---------------- GEMM1: h = gelu(xb[routes] @ W1t^T + b1) ------------------
// LDS: unpadded [128][64] per operand, XOR-chunk swizzle; global_load_lds x16B.
// h layout: [e][fb=f/64][slot][64] so gemm2 A-staging is 1KB-contiguous.
__global__ __launch_bounds__(256, 3)
void gemm1_kernel(const unsigned short* __restrict__ xb,
                  const unsigned short* __restrict__ w1t,   // [E][F][D] bf16
                  const float* __restrict__ b1,
                  const int* __restrict__ routes,
                  unsigned short* __restrict__ h) {
  int e = blockIdx.z, mt = blockIdx.y, nt = blockIdx.x;
  __shared__ unsigned short smem[16384];           // As 8192 | Bs 8192
  unsigned short* As = smem;
  unsigned short* Bs = smem + 8192;
  int t = threadIdx.x, lane = t & 63, wave = t >> 6;
  int wm = (wave >> 1) * 64, wn = (wave & 1) * 64;
  int fr = lane & 15, fq = lane >> 4;
  int lrow = lane >> 3, lchunk = (lane & 7) ^ (lrow & 7);
  int sw = fr & 7;

  const unsigned short* aP[4];
  const unsigned short* bP[4];
#pragma unroll
  for (int q = 0; q < 4; q++) {
    int m = wave * 4 + q;
    int row = m * 8 + lrow;
    int token = routes[e * KCAP + mt * 128 + row];
    aP[q] = xb + (size_t)token * DIM + lchunk * 8;
    bP[q] = w1t + ((size_t)e * FDIM + nt * 128 + row) * DIM + lchunk * 8;
  }

  floatx4 acc[4][4];
#pragma unroll
  for (int i = 0; i < 4; i++)
#pragma unroll
    for (int j = 0; j < 4; j++) acc[i][j] = (floatx4)0.0f;

  for (int k0 = 0; k0 < DIM; k0 += 64) {
    __syncthreads();
#pragma unroll
    for (int q = 0; q < 4; q++) {
      int m = wave * 4 + q;
      ld2lds16(aP[q] + k0, As + m * 512);
      ld2lds16(bP[q] + k0, Bs + m * 512);
    }
    __syncthreads();
#pragma unroll
    for (int ks = 0; ks < 2; ks++) {
      bf16x8 af[4], bf[4];
      int cs = ((ks << 2) | fq) ^ sw;
#pragma unroll
      for (int i = 0; i < 4; i++)
        af[i] = *(const bf16x8*)&As[(wm + i * 16 + fr) * 64 + cs * 8];
#pragma unroll
      for (int j = 0; j < 4; j++)
        bf[j] = *(const bf16x8*)&Bs[(wn + j * 16 + fr) * 64 + cs * 8];
#pragma unroll
      for (int i = 0; i < 4; i++)
#pragma unroll
        for (int j = 0; j < 4; j++)
          acc[i][j] = __builtin_amdgcn_mfma_f32_16x16x32_bf16(af[i], bf[j], acc[i][j], 0, 0, 0);
    }
  }

  float bias[4];
#pragma unroll
  for (int j = 0; j < 4; j++) bias[j] = b1[e * FDIM + nt * 128 + wn + j * 16 + fr];
  int fb = nt * 2 + (wn >> 6);
  size_t hbase = (((size_t)e * 64 + fb) * KCAP + mt * 128) * 64;
#pragma unroll
  for (int i = 0; i < 4; i++) {
#pragma unroll
    for (int r = 0; r < 4; r++) {
      int lr = wm + i * 16 + fq * 4 + r;
#pragma unroll
      for (int j = 0; j < 4; j++) {
        float v = acc[i][j][r] + bias[j];
        float u = 0.7978845608028654f * (v + 0.044715f * v * v * v);
        float g = v * __builtin_amdgcn_rcpf(1.0f + __expf(-2.0f * u));
        h[hbase + (size_t)lr * 64 + j * 16 + fr] = f2bf(g);
      }
    }
  }
}

// ------- GEMM2 split-K=2: partial[s][slot][d] = h(half) @ W2t^T (+b2 s==0) --
__global__ __launch_bounds__(256, 3)
void gemm2_kernel(const unsigned short* __restrict__ h,    // [e][fb][slot][64]
                  const unsigned short* __restrict__ w2t,  // [E][D][F] bf16
                  const float* __restrict__ b2,
                  float* __restrict__ partials) {          // [2][4096][1024]
  int e = blockIdx.z >> 1, s = blockIdx.z & 1;
  int mt = blockIdx.y, nt = blockIdx.x;
  __shared__ unsigned short smem[16384];
  unsigned short* As = smem;
  unsigned short* Bs = smem + 8192;
  int t = threadIdx.x, lane = t & 63, wave = t >> 6;
  int wm = (wave >> 1) * 64, wn = (wave & 1) * 64;
  int fr = lane & 15, fq = lane >> 4;
  int lrow = lane >> 3, lchunk = (lane & 7) ^ (lrow & 7);
  int sw = fr & 7;

  const unsigned short* aP[4];
  const unsigned short* bP[4];
#pragma unroll
  for (int q = 0; q < 4; q++) {
    int m = wave * 4 + q;
    int row = m * 8 + lrow;
    aP[q] = h + (((size_t)e * 64 + s * 32) * KCAP + mt * 128 + row) * 64 + lchunk * 8;
    bP[q] = w2t + ((size_t)e * DIM + nt * 128 + row) * FDIM + s * 2048 + lchunk * 8;
  }

  floatx4 acc[4][4];
#pragma unroll
  for (int i = 0; i < 4; i++)
#pragma unroll
    for (int j = 0; j < 4; j++) acc[i][j] = (floatx4)0.0f;

  for (int k0 = 0; k0 < 2048; k0 += 64) {
    __syncthreads();
#pragma unroll
    for (int q = 0; q < 4; q++) {
      int m = wave * 4 + q;
      ld2lds16(aP[q] + (size_t)k0 * 512, As + m * 512);   // next fb stride = 512*64
      ld2lds16(bP[q] + k0, Bs + m * 512);
    }
    __syncthreads();
#pragma unroll
    for (int ks = 0; ks < 2; ks++) {
      bf16x8 af[4], bf[4];
      int cs = ((ks << 2) | fq) ^ sw;
#pragma unroll
      for (int i = 0; i < 4; i++)
        af[i] = *(const bf16x8*)&As[(wm + i * 16 + fr) * 64 + cs * 8];
#pragma unroll
      for (int j = 0; j < 4; j++)
        bf[j] = *(const bf16x8*)&Bs[(wn + j * 16 + fr) * 64 + cs * 8];
#pragma unroll
      for (int i = 0; i < 4; i++)
#pragma unroll
        for (int j = 0; j < 4; j++)
          acc[i][j] = __builtin_amdgcn_mfma_f32_16x16x32_bf16(af[i], bf[j], acc[i][j], 0, 0, 0);
    }
  }

  // epilogue: stage C through LDS (two 128x64 fp32 passes) for coalesced stores
  float* LC = (float*)smem;                       // [128][64] fp32 = 32 KB
  float* outp = partials + (size_t)s * N_TOK * DIM;
  int slotbase = e * KCAP + mt * 128;
  float bias[4];
#pragma unroll
  for (int j = 0; j < 4; j++)
    bias[j] = (s == 0) ? b2[e * DIM + nt * 128 + wn + j * 16 + fr] : 0.0f;
#pragma unroll
  for (int p = 0; p < 2; p++) {
    __syncthreads();
    if ((wn >> 6) == p) {
#pragma unroll
      for (int i = 0; i < 4; i++)
#pragma unroll
        for (int r = 0; r < 4; r++) {
          int lr = wm + i * 16 + fq * 4 + r;
#pragma unroll
          for (int j = 0; j < 4; j++)
            LC[lr * 64 + j * 16 + fr] = acc[i][j][r] + bias[j];
        }
    }
    __syncthreads();
    int row = t >> 1, ch = (t & 1) * 32;
    float* dst = outp + (size_t)(slotbase + row) * DIM + nt * 128 + p * 64 + ch;
#pragma unroll
    for (int qq = 0; qq < 8; qq++)
      *(float4*)&dst[qq * 4] = *(const float4*)&LC[row * 64 + ch + qq * 4];
  }
}

// -------- combine: out[token] = sum_slots val[slot] * sum_s partial[s][slot] -
__global__ __launch_bounds__(256)
void combine_kernel(const float* __restrict__ partials, const int* __restrict__ counts,
                    const int* __restrict__ inv, const float* __restrict__ vals,
                    float* __restrict__ out) {
  int token = blockIdx.x;
  int t = threadIdx.x;
  int c = counts[token];
  float4 acc = {0.f, 0.f, 0.f, 0.f};
  for (int i = 0; i < c; i++) {
    int slot = inv[token * NEXP + i];
    float vs = vals[slot];
    const float* base = partials + (size_t)slot * DIM + t * 4;
#pragma unroll
    for (int s = 0; s < 2; s++) {
      float4 v = *(const float4*)&base[(size_t)s * N_TOK * DIM];
      acc.x += vs * v.x; acc.y += vs * v.y; acc.z += vs * v.z; acc.w += vs * v.w;
    }
  }
  *(float4*)&out[(size_t)token * DIM + t * 4] = acc;
}

extern "C" void kernel_launch(void* const* d_in, const int* in_sizes, int n_in,
                              void* d_out, int out_size, void* d_ws, size_t ws_size,
                              hipStream_t stream) {
  const float* x  = (const float*)d_in[0];
  const float* Ws = (const float*)d_in[1];
  const float* bs = (const float*)d_in[2];
  const float* W1 = (const float*)d_in[3];
  const float* b1 = (const float*)d_in[4];
  const float* W2 = (const float*)d_in[5];
  const float* b2 = (const float*)d_in[6];
  float* out = (float*)d_out;

  char* ws = (char*)d_ws;
  unsigned short* wt = (unsigned short*)ws; ws += (size_t)NEXP * FDIM * DIM * 2;  // 67 MB (shared W1t/W2t)
  unsigned short* h  = (unsigned short*)ws; ws += (size_t)NEXP * KCAP * FDIM * 2; // 33.5 MB
  // xb (8.4 MB) aliases the partials region (33.6 MB): xb dead before gemm2 writes
  char* pshare = ws; ws += (size_t)2 * N_TOK * DIM * 4;
  unsigned short* xb = (unsigned short*)pshare;
  float* partials    = (float*)pshare;
  float* probs  = (float*)ws; ws += (size_t)NEXP * N_TOK * 4;
  int*   routes = (int*)ws;   ws += NEXP * KCAP * 4;
  float* vals   = (float*)ws; ws += NEXP * KCAP * 4;
  int*   counts = (int*)ws;   ws += N_TOK * 4;
  int*   inv    = (int*)ws;   ws += N_TOK * NEXP * 4;

  hipMemsetAsync(counts, 0, N_TOK * sizeof(int), stream);
  router_kernel<<<N_TOK / 4, 256, 0, stream>>>(x, Ws, bs, probs);
  topk_kernel<<<NEXP, 1024, 0, stream>>>(probs, routes, vals);
  invidx_kernel<<<NEXP * KCAP / 256, 256, 0, stream>>>(routes, counts, inv);
  convx_kernel<<<N_TOK * DIM / 1024, 256, 0, stream>>>(x, xb);
  // W1 [E][D][F] fp32 -> wt [E][F][D] bf16
  transpose_kernel<<<dim3(FDIM / 32, DIM / 32, NEXP), 256, 0, stream>>>(W1, wt, DIM, FDIM);
  gemm1_kernel<<<dim3(FDIM / 128, KCAP / 128, NEXP), 256, 0, stream>>>(xb, wt, b1, routes, h);
  // W2 [E][F][D] fp32 -> wt [E][D][F] bf16
  transpose_kernel<<<dim3(DIM / 32, FDIM / 32, NEXP), 256, 0, stream>>>(W2, wt, FDIM, DIM);
  gemm2_kernel<<<dim3(DIM / 128, KCAP / 128, NEXP * 2), 256, 0, stream>>>(h, wt, b2, partials);
  combine_kernel<<<N_TOK, 256, 0, stream>>>(partials, counts, inv, vals, out);
}